// Round 9
// baseline (220.953 us; speedup 1.0000x reference)
//
#include <hip/hip_runtime.h>
#include <hip/hip_bf16.h>

// spatial_attention: out = [softmax_weights | H] @ Wcat^T + bias
//   Domain is uniform (verified at runtime by k0_check) -> fast path:
//   w = relu(dval - dist), no gathers, bear/head never read.
//   K0 : Wbf = bf16(W); k0_check -> {dval, uniform}
//   K1 : P1T[b][d][j] = bf16( (H W1^T)[j][d] )   (32 MB, transposed)
//   K2 : m97-structure fused GEMM. Single 32KB sB staged via global_load_lds
//        (linear dest + pre-swizzled source, XOR-swizzled ds_read). 64-row
//        blocks, 8 waves (wave = 16 rows x 128 d), 4 blocks/CU.
// Workspace: Wbf 512KB @0 ; flag @512KB ; P1T 32MB @1MB

typedef __attribute__((ext_vector_type(4))) float  f32x4;
typedef __attribute__((ext_vector_type(8))) short  bf16x8;
typedef __attribute__((ext_vector_type(4))) short  bf16x4;

#define EPSC 1e-14f

__device__ __forceinline__ short f2bf(float v) {
  __hip_bfloat16 h = __float2bfloat16(v);
  return *reinterpret_cast<short*>(&h);
}

__device__ __forceinline__ void gload16(const void* g, void* l) {
  __builtin_amdgcn_global_load_lds(
      (const __attribute__((address_space(1))) void*)g,
      (__attribute__((address_space(3))) void*)l, 16, 0, 0);
}

// ---------------- K0: W fp32 -> bf16 ----------------
__global__ void k0_pack(const float* __restrict__ W, short* __restrict__ Wbf) {
  int idx = blockIdx.x * 256 + threadIdx.x;
  f32x4 v = *(const f32x4*)(W + (size_t)idx * 4);
  bf16x4 pk;
  pk[0] = f2bf(v[0]); pk[1] = f2bf(v[1]); pk[2] = f2bf(v[2]); pk[3] = f2bf(v[3]);
  *(bf16x4*)(Wbf + (size_t)idx * 4) = pk;
}

// ---------------- K0b: domain uniformity check ----------------
__global__ void k0_check(const float* __restrict__ domain, float* __restrict__ flag) {
  __shared__ int s_ok[4];
  const int t = threadIdx.x;
  float v0 = domain[0];
  bool ok = true;
  for (int x = t; x < 72 * 72; x += 256) ok = ok && (domain[x] == v0);
  unsigned long long m = __ballot(ok);
  if ((t & 63) == 0) s_ok[t >> 6] = (m == ~0ull) ? 1 : 0;
  __syncthreads();
  if (t == 0) {
    flag[0] = v0;
    flag[1] = (s_ok[0] && s_ok[1] && s_ok[2] && s_ok[3]) ? 1.f : 0.f;
  }
}

// ---------------- K1: P1T = (H @ W1^T)^T, grid 1024, block 512 ----------------
__global__ __launch_bounds__(512) void k1_proj(
    const float* __restrict__ H, const short* __restrict__ Wbf,
    short* __restrict__ P1T) {
  extern __shared__ char sm[];
  char* sA = sm;                 // 64 rows x 64 k bf16, 144B stride
  char* sB = sm + 9216;          // 256 d x 64 k bf16, 144B stride
  const int t  = threadIdx.x;
  const int n0 = blockIdx.x * 64;
  const int b  = n0 >> 8;
  const int jb = n0 & 255;

  const int wid = t >> 6, l = t & 63;
  const int wn = wid >> 2, wc = wid & 3;
  const int lr = l & 15, lg = l >> 4;
  f32x4 acc[2][4] = {};

  for (int kk = 0; kk < 256; kk += 64) {
    __syncthreads();
    #pragma unroll
    for (int p = 0; p < 2; ++p) {
      int q = t + 512 * p;
      int j = q >> 4, seg = q & 15;
      f32x4 hv = *(const f32x4*)(H + ((size_t)(n0 + j)) * 256 + kk + seg * 4);
      bf16x4 pk;
      pk[0] = f2bf(hv[0]); pk[1] = f2bf(hv[1]); pk[2] = f2bf(hv[2]); pk[3] = f2bf(hv[3]);
      *(bf16x4*)(sA + j * 144 + seg * 8) = pk;
    }
    #pragma unroll
    for (int p = 0; p < 4; ++p) {
      int z = t + 512 * p;
      int d = z >> 3, s = z & 7;
      bf16x8 v = *(const bf16x8*)(Wbf + (size_t)d * 512 + kk + s * 8);
      *(bf16x8*)(sB + d * 144 + s * 16) = v;
    }
    __syncthreads();
    #pragma unroll
    for (int sub = 0; sub < 2; ++sub) {
      bf16x8 a[2], bb[4];
      #pragma unroll
      for (int m = 0; m < 2; ++m) {
        int row = wn * 32 + m * 16 + lr;
        a[m] = *(const bf16x8*)(sA + row * 144 + sub * 64 + lg * 16);
      }
      #pragma unroll
      for (int f = 0; f < 4; ++f) {
        int d = wc * 64 + f * 16 + lr;
        bb[f] = *(const bf16x8*)(sB + d * 144 + sub * 64 + lg * 16);
      }
      #pragma unroll
      for (int m = 0; m < 2; ++m) {
        #pragma unroll
        for (int f = 0; f < 4; ++f)
          acc[m][f] = __builtin_amdgcn_mfma_f32_16x16x32_bf16(a[m], bb[f], acc[m][f], 0, 0, 0);
      }
    }
  }

  #pragma unroll
  for (int m = 0; m < 2; ++m) {
    int jl = wn * 32 + m * 16 + lg * 4;
    #pragma unroll
    for (int f = 0; f < 4; ++f) {
      int d = wc * 64 + f * 16 + lr;
      f32x4 v = acc[m][f];
      bf16x4 pk;
      pk[0] = f2bf(v[0]); pk[1] = f2bf(v[1]); pk[2] = f2bf(v[2]); pk[3] = f2bf(v[3]);
      *(bf16x4*)(P1T + (size_t)b * 65536 + (size_t)d * 256 + jb + jl) = pk;
    }
  }
}

// weight numerators for 8 k-elements (uniform-domain fast path)
__device__ __forceinline__ bf16x8 pack8(
    f32x4 da, f32x4 db, f32x4 ma, f32x4 mb,
    int gk, int i, float mI, float dval, float& rs) {
  bf16x8 pk;
  #pragma unroll
  for (int e = 0; e < 4; ++e) {
    float wv = fmaxf(dval - da[e], 0.f);
    bool valid = (i != gk + e) && (mI != 0.f) && (ma[e] != 0.f);
    float ex = (wv > 0.f) ? __expf(wv) : 0.f;
    ex = valid ? ex : 0.f;
    rs += ex;
    pk[e] = f2bf(valid ? (ex + EPSC) : 0.f);
  }
  #pragma unroll
  for (int e = 0; e < 4; ++e) {
    float wv = fmaxf(dval - db[e], 0.f);
    bool valid = (i != gk + 4 + e) && (mI != 0.f) && (mb[e] != 0.f);
    float ex = (wv > 0.f) ? __expf(wv) : 0.f;
    ex = valid ? ex : 0.f;
    rs += ex;
    pk[4 + e] = f2bf(valid ? (ex + EPSC) : 0.f);
  }
  return pk;
}

// gather fallback (non-uniform domain; correctness only)
__device__ __forceinline__ bf16x8 pack8g(
    const float* __restrict__ dist, const float* __restrict__ bear,
    const float* __restrict__ head, const float* __restrict__ domain,
    f32x4 ma, f32x4 mb, size_t base, int gk, int i, float mI, float& rs) {
  f32x4 d0 = *(const f32x4*)(dist + base + gk);
  f32x4 d1 = *(const f32x4*)(dist + base + gk + 4);
  f32x4 b0 = *(const f32x4*)(bear + base + gk);
  f32x4 b1 = *(const f32x4*)(bear + base + gk + 4);
  f32x4 h0 = *(const f32x4*)(head + base + gk);
  f32x4 h1 = *(const f32x4*)(head + base + gk + 4);
  bf16x8 pk;
  #pragma unroll
  for (int e = 0; e < 4; ++e) {
    float f1 = fminf(fmaxf(floorf((h0[e] + 2.5f) * 0.2f), 0.f), 71.f);
    float f2 = fminf(fmaxf(floorf((b0[e] + 2.5f) * 0.2f), 0.f), 71.f);
    float wv = fmaxf(domain[(int)(f1 * 72.f + f2)] - d0[e], 0.f);
    bool valid = (i != gk + e) && (mI != 0.f) && (ma[e] != 0.f);
    float ex = (wv > 0.f) ? __expf(wv) : 0.f;
    ex = valid ? ex : 0.f;
    rs += ex;
    pk[e] = f2bf(valid ? (ex + EPSC) : 0.f);
  }
  #pragma unroll
  for (int e = 0; e < 4; ++e) {
    float f1 = fminf(fmaxf(floorf((h1[e] + 2.5f) * 0.2f), 0.f), 71.f);
    float f2 = fminf(fmaxf(floorf((b1[e] + 2.5f) * 0.2f), 0.f), 71.f);
    float wv = fmaxf(domain[(int)(f1 * 72.f + f2)] - d1[e], 0.f);
    bool valid = (i != gk + 4 + e) && (mI != 0.f) && (mb[e] != 0.f);
    float ex = (wv > 0.f) ? __expf(wv) : 0.f;
    ex = valid ? ex : 0.f;
    rs += ex;
    pk[4 + e] = f2bf(valid ? (ex + EPSC) : 0.f);
  }
  return pk;
}

// ---------------- K2 fused: grid 1024 (b = blk>>2, i0 = (blk&3)*64), block 512 ----------------
// 8 waves = (wr 0..3) x (wc 0..1); wave = 16 rows x 128 d, acc[8].
// sB [256 d][128B] linear, staged by global_load_lds with pre-swizzled source;
// ds_read XOR-swizzled -> 2-way conflicts. LDS 34816 B -> 4 blocks/CU.
__global__ __launch_bounds__(512, 8) void k2_fused(
    const float* __restrict__ dist, const float* __restrict__ bear,
    const float* __restrict__ head, const float* __restrict__ seqmask,
    const float* __restrict__ domain, const short* __restrict__ P1T,
    const short* __restrict__ Wbf, const float* __restrict__ H,
    const float* __restrict__ bias, const float* __restrict__ uflag,
    float* __restrict__ out) {
  extern __shared__ char sm[];
  char*  sB    = sm;                      // [256][128] bf16, XOR-swizzled slots
  float* sMask = (float*)(sm + 32768);
  float* sBias = (float*)(sm + 33792);
  const int t  = threadIdx.x;
  const int b  = blockIdx.x >> 2;
  const int i0 = (blockIdx.x & 3) * 64;

  const int wid = t >> 6, l = t & 63;
  const int lr = l & 15, lg = l >> 4;
  const int wr = wid >> 1, wc = wid & 1;
  const int i  = i0 + wr * 16 + lr;
  const size_t base = ((size_t)b * 256 + i) * 256;
  const short* __restrict__ P1b = P1T + (size_t)b * 65536;

  // stage-source swizzle pieces: lane l -> phys row r3, phys slot sl; the data
  // placed there must be logical slot sl^r3 (so swizzled reads find it).
  const int r3 = l >> 3, sl = l & 7;
  const int sswz = (sl ^ r3) * 8;         // element (short) offset in 64-k chunk

  const float dval = uflag[0];
  const bool  uni  = uflag[1] != 0.f;
  const float mI = seqmask[b * 256 + i];

  // ---- prologue: stage chunk 0 of P1T; mask/bias to LDS ----
  #pragma unroll
  for (int p = 0; p < 4; ++p) {
    int dd = wid * 8 + r3 + 64 * p;
    gload16(P1b + (size_t)dd * 256 + sswz, sB + (wid * 8 + 64 * p) * 128);
  }
  if (t < 256) { sMask[t] = seqmask[b * 256 + t]; sBias[t] = bias[t]; }

  f32x4 acc[8] = {};
  float rs = 0.f;
  const int sw = (lr & 7) << 4;

  // ---- GEMM1: weights (A-frag regs) @ P1T, chunks 0..3 ----
  for (int c = 0; c < 4; ++c) {
    __syncthreads();                      // stage(c) + prev reads drained
    const int gk0 = c * 64 + lg * 8;
    const int gk1 = gk0 + 32;
    f32x4 m0 = *(const f32x4*)(sMask + gk0);
    f32x4 m1 = *(const f32x4*)(sMask + gk0 + 4);
    f32x4 m2 = *(const f32x4*)(sMask + gk1);
    f32x4 m3 = *(const f32x4*)(sMask + gk1 + 4);
    bf16x8 pk0, pk1;
    if (uni) {
      f32x4 d0 = *(const f32x4*)(dist + base + gk0);
      f32x4 d1 = *(const f32x4*)(dist + base + gk0 + 4);
      f32x4 d2 = *(const f32x4*)(dist + base + gk1);
      f32x4 d3 = *(const f32x4*)(dist + base + gk1 + 4);
      pk0 = pack8(d0, d1, m0, m1, gk0, i, mI, dval, rs);
      pk1 = pack8(d2, d3, m2, m3, gk1, i, mI, dval, rs);
    } else {
      pk0 = pack8g(dist, bear, head, domain, m0, m1, base, gk0, i, mI, rs);
      pk1 = pack8g(dist, bear, head, domain, m2, m3, base, gk1, i, mI, rs);
    }
    #pragma unroll
    for (int n = 0; n < 8; ++n) {
      const int d = wc * 128 + n * 16 + lr;
      bf16x8 b0 = *(const bf16x8*)(sB + d * 128 + ((lg * 16) ^ sw));
      bf16x8 b1 = *(const bf16x8*)(sB + d * 128 + ((64 + lg * 16) ^ sw));
      acc[n] = __builtin_amdgcn_mfma_f32_16x16x32_bf16(pk0, b0, acc[n], 0, 0, 0);
      acc[n] = __builtin_amdgcn_mfma_f32_16x16x32_bf16(pk1, b1, acc[n], 0, 0, 0);
    }
    __syncthreads();                      // all waves done reading sB
    if (c < 3) {
      #pragma unroll
      for (int p = 0; p < 4; ++p) {
        int dd = wid * 8 + r3 + 64 * p;
        gload16(P1b + (size_t)dd * 256 + (c + 1) * 64 + sswz,
                sB + (wid * 8 + 64 * p) * 128);
      }
    } else {
      #pragma unroll
      for (int p = 0; p < 4; ++p) {
        int dd = wid * 8 + r3 + 64 * p;
        gload16(Wbf + (size_t)dd * 512 + 256 + sswz,
                sB + (wid * 8 + 64 * p) * 128);
      }
    }
  }

  // ---- row-sum reduce (across lg) and scale accumulators ----
  rs += __shfl_xor(rs, 16, 64);
  rs += __shfl_xor(rs, 32, 64);
  const float scale = 1.0f / (rs + 257.0f * EPSC);
  float srow[4];
  #pragma unroll
  for (int r = 0; r < 4; ++r) srow[r] = __shfl(scale, lg * 4 + r, 64);
  #pragma unroll
  for (int n = 0; n < 8; ++n) {
    acc[n][0] *= srow[0]; acc[n][1] *= srow[1];
    acc[n][2] *= srow[2]; acc[n][3] *= srow[3];
  }

  // ---- GEMM2: bf16(H) @ W2, chunks 0..3 ----
  for (int c = 0; c < 4; ++c) {
    __syncthreads();
    const int gk0 = c * 64 + lg * 8;
    const int gk1 = gk0 + 32;
    f32x4 x0 = *(const f32x4*)(H + base + gk0);
    f32x4 x1 = *(const f32x4*)(H + base + gk0 + 4);
    f32x4 y0 = *(const f32x4*)(H + base + gk1);
    f32x4 y1 = *(const f32x4*)(H + base + gk1 + 4);
    bf16x8 a0, a1;
    a0[0] = f2bf(x0[0]); a0[1] = f2bf(x0[1]); a0[2] = f2bf(x0[2]); a0[3] = f2bf(x0[3]);
    a0[4] = f2bf(x1[0]); a0[5] = f2bf(x1[1]); a0[6] = f2bf(x1[2]); a0[7] = f2bf(x1[3]);
    a1[0] = f2bf(y0[0]); a1[1] = f2bf(y0[1]); a1[2] = f2bf(y0[2]); a1[3] = f2bf(y0[3]);
    a1[4] = f2bf(y1[0]); a1[5] = f2bf(y1[1]); a1[6] = f2bf(y1[2]); a1[7] = f2bf(y1[3]);
    #pragma unroll
    for (int n = 0; n < 8; ++n) {
      const int d = wc * 128 + n * 16 + lr;
      bf16x8 b0 = *(const bf16x8*)(sB + d * 128 + ((lg * 16) ^ sw));
      bf16x8 b1 = *(const bf16x8*)(sB + d * 128 + ((64 + lg * 16) ^ sw));
      acc[n] = __builtin_amdgcn_mfma_f32_16x16x32_bf16(a0, b0, acc[n], 0, 0, 0);
      acc[n] = __builtin_amdgcn_mfma_f32_16x16x32_bf16(a1, b1, acc[n], 0, 0, 0);
    }
    __syncthreads();
    if (c < 3) {
      #pragma unroll
      for (int p = 0; p < 4; ++p) {
        int dd = wid * 8 + r3 + 64 * p;
        gload16(Wbf + (size_t)dd * 512 + 256 + (c + 1) * 64 + sswz,
                sB + (wid * 8 + 64 * p) * 128);
      }
    }
  }

  // ---- epilogue: + bias, store ----
  #pragma unroll
  for (int n = 0; n < 8; ++n) {
    int d = wc * 128 + n * 16 + lr;
    float bs = sBias[d];
    #pragma unroll
    for (int r = 0; r < 4; ++r) {
      int row = i0 + wr * 16 + lg * 4 + r;
      out[((size_t)b * 256 + row) * 256 + d] = acc[n][r] + bs;
    }
  }
}

extern "C" void kernel_launch(void* const* d_in, const int* in_sizes, int n_in,
                              void* d_out, int out_size, void* d_ws, size_t ws_size,
                              hipStream_t stream) {
  const float* hidden  = (const float*)d_in[0];
  const float* dist    = (const float*)d_in[1];
  const float* bear    = (const float*)d_in[2];
  const float* head    = (const float*)d_in[3];
  const float* seqmask = (const float*)d_in[4];
  const float* domain  = (const float*)d_in[5];
  const float* W       = (const float*)d_in[6];
  const float* bias    = (const float*)d_in[7];
  float* out = (float*)d_out;

  char* ws = (char*)d_ws;
  short* Wbf  = (short*)ws;                                  // 512 KB
  float* flag = (float*)(ws + 524288);                       // 2 floats
  short* P1T  = (short*)(ws + (1u << 20));                   // 32 MB

  k0_pack<<<128, 256, 0, stream>>>(W, Wbf);
  k0_check<<<1, 256, 0, stream>>>(domain, flag);
  k1_proj<<<1024, 512, 46080, stream>>>(hidden, Wbf, P1T);
  k2_fused<<<1024, 512, 34816, stream>>>(dist, bear, head, seqmask, domain,
                                         P1T, Wbf, hidden, bias, flag, out);
}

// Round 10
// 113.605 us; speedup vs baseline: 1.9449x; 1.9449x over previous
//
#include <hip/hip_runtime.h>
#include <hip/hip_bf16.h>

// spatial_attention: out = [scaled_weights | H] @ Wcat^T + bias   (K = 512 concat GEMM)
//   Domain is uniform (runtime-verified) -> K2a fast path: w = relu(dval - dist),
//   no gathers, bear/head never read.
//   K0 : Wbf = bf16(W); k0_check -> {dval, uniform}
//   K1 : P1T[b][d][j] = bf16( (H W1^T)[j][d] )        (32 MB, transposed)
//   K2a: weBuf[b][i][j] = bf16( pre-scaled weights ). Wave-per-row: 64 lanes x f32x4
//        = one 256-col row; 1 dist load/lane; 6-shfl reduce; no LDS loop, no barriers.
//   K2b: out = [weBuf | bf16(H)] @ [P1T | W2] + bias  (R2-proven structure)
// Workspace: Wbf 512KB @0 ; flag @512KB ; P1T 32MB @1MB ; weBuf 32MB @33MB

typedef __attribute__((ext_vector_type(4))) float  f32x4;
typedef __attribute__((ext_vector_type(8))) short  bf16x8;
typedef __attribute__((ext_vector_type(4))) short  bf16x4;

#define EPSC 1e-14f

__device__ __forceinline__ short f2bf(float v) {
  __hip_bfloat16 h = __float2bfloat16(v);
  return *reinterpret_cast<short*>(&h);
}

// ---------------- K0: W fp32 -> bf16 ----------------
__global__ void k0_pack(const float* __restrict__ W, short* __restrict__ Wbf) {
  int idx = blockIdx.x * 256 + threadIdx.x;
  f32x4 v = *(const f32x4*)(W + (size_t)idx * 4);
  bf16x4 pk;
  pk[0] = f2bf(v[0]); pk[1] = f2bf(v[1]); pk[2] = f2bf(v[2]); pk[3] = f2bf(v[3]);
  *(bf16x4*)(Wbf + (size_t)idx * 4) = pk;
}

// ---------------- K0b: domain uniformity check ----------------
__global__ void k0_check(const float* __restrict__ domain, float* __restrict__ flag) {
  __shared__ int s_ok[4];
  const int t = threadIdx.x;
  float v0 = domain[0];
  bool ok = true;
  for (int x = t; x < 72 * 72; x += 256) ok = ok && (domain[x] == v0);
  unsigned long long m = __ballot(ok);
  if ((t & 63) == 0) s_ok[t >> 6] = (m == ~0ull) ? 1 : 0;
  __syncthreads();
  if (t == 0) {
    flag[0] = v0;
    flag[1] = (s_ok[0] && s_ok[1] && s_ok[2] && s_ok[3]) ? 1.f : 0.f;
  }
}

// ---------------- K1: P1T = (H @ W1^T)^T, grid 1024 (64 j-rows), block 512 ----------------
__global__ __launch_bounds__(512) void k1_proj(
    const float* __restrict__ H, const short* __restrict__ Wbf,
    short* __restrict__ P1T) {
  extern __shared__ char sm[];
  char* sA = sm;                 // 64 rows x 64 k bf16, 144B stride
  char* sB = sm + 9216;          // 256 d x 64 k bf16, 144B stride
  const int t  = threadIdx.x;
  const int n0 = blockIdx.x * 64;
  const int b  = n0 >> 8;
  const int jb = n0 & 255;

  const int wid = t >> 6, l = t & 63;
  const int wn = wid >> 2, wc = wid & 3;
  const int lr = l & 15, lg = l >> 4;
  f32x4 acc[2][4] = {};

  for (int kk = 0; kk < 256; kk += 64) {
    __syncthreads();
    #pragma unroll
    for (int p = 0; p < 2; ++p) {
      int q = t + 512 * p;
      int j = q >> 4, seg = q & 15;
      f32x4 hv = *(const f32x4*)(H + ((size_t)(n0 + j)) * 256 + kk + seg * 4);
      bf16x4 pk;
      pk[0] = f2bf(hv[0]); pk[1] = f2bf(hv[1]); pk[2] = f2bf(hv[2]); pk[3] = f2bf(hv[3]);
      *(bf16x4*)(sA + j * 144 + seg * 8) = pk;
    }
    #pragma unroll
    for (int p = 0; p < 4; ++p) {
      int z = t + 512 * p;
      int d = z >> 3, s = z & 7;
      bf16x8 v = *(const bf16x8*)(Wbf + (size_t)d * 512 + kk + s * 8);
      *(bf16x8*)(sB + d * 144 + s * 16) = v;
    }
    __syncthreads();
    #pragma unroll
    for (int sub = 0; sub < 2; ++sub) {
      bf16x8 a[2], bb[4];
      #pragma unroll
      for (int m = 0; m < 2; ++m) {
        int row = wn * 32 + m * 16 + lr;
        a[m] = *(const bf16x8*)(sA + row * 144 + sub * 64 + lg * 16);
      }
      #pragma unroll
      for (int f = 0; f < 4; ++f) {
        int d = wc * 64 + f * 16 + lr;
        bb[f] = *(const bf16x8*)(sB + d * 144 + sub * 64 + lg * 16);
      }
      #pragma unroll
      for (int m = 0; m < 2; ++m) {
        #pragma unroll
        for (int f = 0; f < 4; ++f)
          acc[m][f] = __builtin_amdgcn_mfma_f32_16x16x32_bf16(a[m], bb[f], acc[m][f], 0, 0, 0);
      }
    }
  }

  #pragma unroll
  for (int m = 0; m < 2; ++m) {
    int jl = wn * 32 + m * 16 + lg * 4;
    #pragma unroll
    for (int f = 0; f < 4; ++f) {
      int d = wc * 64 + f * 16 + lr;
      f32x4 v = acc[m][f];
      bf16x4 pk;
      pk[0] = f2bf(v[0]); pk[1] = f2bf(v[1]); pk[2] = f2bf(v[2]); pk[3] = f2bf(v[3]);
      *(bf16x4*)(P1T + (size_t)b * 65536 + (size_t)d * 256 + jb + jl) = pk;
    }
  }
}

// ---------------- K2a: pre-scaled weights, wave-per-row ----------------
// grid 2048 (b = blk>>3, i0 = (blk&7)*32), block 256 = 4 waves; wave does 8 rows.
// Per row: one f32x4 dist load per lane (64 lanes = full 256-col row),
// ~50 VALU, 6-shfl reduce, one bf16x4 store. No LDS in loop, no barriers.
__global__ __launch_bounds__(256) void k2a_weights(
    const float* __restrict__ dist, const float* __restrict__ bear,
    const float* __restrict__ head, const float* __restrict__ seqmask,
    const float* __restrict__ domain, const float* __restrict__ uflag,
    short* __restrict__ weBuf) {
  __shared__ float sMask[256];
  const int t = threadIdx.x;
  const int b = blockIdx.x >> 3;
  const int i0 = (blockIdx.x & 7) * 32;
  if (t < 256) sMask[t] = seqmask[b * 256 + t];
  __syncthreads();

  const int w = t >> 6, l = t & 63;
  const int j0 = l * 4;
  const float dval = uflag[0];
  const bool  uni  = uflag[1] != 0.f;
  const f32x4 mj = *(const f32x4*)(sMask + j0);

  // all 8 rows' dist slices issued upfront (32 VGPR in flight)
  f32x4 dv[8];
  #pragma unroll
  for (int rr = 0; rr < 8; ++rr) {
    int i = i0 + w * 8 + rr;
    dv[rr] = *(const f32x4*)(dist + ((size_t)b * 256 + i) * 256 + j0);
  }

  #pragma unroll
  for (int rr = 0; rr < 8; ++rr) {
    const int i = i0 + w * 8 + rr;
    const float mI = sMask[i];
    const size_t base = ((size_t)b * 256 + i) * 256;
    float ev[4];
    float rs = 0.f;
    if (uni) {
      #pragma unroll
      for (int e = 0; e < 4; ++e) {
        float wv = fmaxf(dval - dv[rr][e], 0.f);
        bool valid = (i != j0 + e) && (mI != 0.f) && (mj[e] != 0.f);
        float ex = (wv > 0.f) ? __expf(wv) : 0.f;
        ex = valid ? ex : 0.f;
        rs += ex;
        ev[e] = valid ? (ex + EPSC) : 0.f;
      }
    } else {
      f32x4 bv = *(const f32x4*)(bear + base + j0);
      f32x4 hv = *(const f32x4*)(head + base + j0);
      #pragma unroll
      for (int e = 0; e < 4; ++e) {
        float f1 = fminf(fmaxf(floorf((hv[e] + 2.5f) * 0.2f), 0.f), 71.f);
        float f2 = fminf(fmaxf(floorf((bv[e] + 2.5f) * 0.2f), 0.f), 71.f);
        float wv = fmaxf(domain[(int)(f1 * 72.f + f2)] - dv[rr][e], 0.f);
        bool valid = (i != j0 + e) && (mI != 0.f) && (mj[e] != 0.f);
        float ex = (wv > 0.f) ? __expf(wv) : 0.f;
        ex = valid ? ex : 0.f;
        rs += ex;
        ev[e] = valid ? (ex + EPSC) : 0.f;
      }
    }
    // full-wave sum
    rs += __shfl_xor(rs, 1, 64);
    rs += __shfl_xor(rs, 2, 64);
    rs += __shfl_xor(rs, 4, 64);
    rs += __shfl_xor(rs, 8, 64);
    rs += __shfl_xor(rs, 16, 64);
    rs += __shfl_xor(rs, 32, 64);
    const float scale = 1.0f / (rs + 257.0f * EPSC);
    bf16x4 pk;
    pk[0] = f2bf(ev[0] * scale); pk[1] = f2bf(ev[1] * scale);
    pk[2] = f2bf(ev[2] * scale); pk[3] = f2bf(ev[3] * scale);
    *(bf16x4*)(weBuf + base + j0) = pk;
  }
}

// ---------------- K2b: out = [weBuf | bf16(H)] @ [P1T | W2] + bias, K=512 ----------------
// grid 512 (b = blk>>1, i0 = (blk&1)*128), block 512. LDS 56320 -> 2 blocks/CU.
__global__ __launch_bounds__(512) void k2b_gemm(
    const short* __restrict__ weBuf, const float* __restrict__ H,
    const short* __restrict__ P1T, const short* __restrict__ Wbf,
    const float* __restrict__ bias, float* __restrict__ out) {
  extern __shared__ char sm[];
  char*  sA    = sm;                 // 128 rows x 64 k bf16, 144B stride
  char*  sB    = sm + 18432;         // 256 d  x 64 k bf16, 144B stride
  float* sBias = (float*)(sm + 18432 + 36864);
  const int t  = threadIdx.x;
  const int b  = blockIdx.x >> 1;
  const int i0 = (blockIdx.x & 1) * 128;

  if (t < 256) sBias[t] = bias[t];

  const int wid = t >> 6, l = t & 63;
  const int wm = wid >> 1, wn = wid & 1;
  const int lr = l & 15, lg = l >> 4;
  f32x4 acc[2][8] = {};

  for (int kk = 0; kk < 512; kk += 64) {
    __syncthreads();
    if (kk < 256) {
      #pragma unroll
      for (int p = 0; p < 2; ++p) {
        int z = t + 512 * p;
        int row = z >> 3, s = z & 7;
        bf16x8 v = *(const bf16x8*)(weBuf + ((size_t)b * 256 + i0 + row) * 256 + kk + s * 8);
        *(bf16x8*)(sA + row * 144 + s * 16) = v;
      }
    } else {
      #pragma unroll
      for (int p = 0; p < 2; ++p) {
        int z = t + 512 * p;
        int row = z >> 3, s = z & 7;
        const float* src = H + ((size_t)b * 256 + i0 + row) * 256 + (kk - 256) + s * 8;
        f32x4 h0 = *(const f32x4*)(src);
        f32x4 h1 = *(const f32x4*)(src + 4);
        bf16x8 pk;
        pk[0] = f2bf(h0[0]); pk[1] = f2bf(h0[1]); pk[2] = f2bf(h0[2]); pk[3] = f2bf(h0[3]);
        pk[4] = f2bf(h1[0]); pk[5] = f2bf(h1[1]); pk[6] = f2bf(h1[2]); pk[7] = f2bf(h1[3]);
        *(bf16x8*)(sA + row * 144 + s * 16) = pk;
      }
    }
    #pragma unroll
    for (int p = 0; p < 4; ++p) {
      int z = t + 512 * p;
      int d = z >> 3, s = z & 7;
      bf16x8 v;
      if (kk < 256) v = *(const bf16x8*)(P1T + (size_t)b * 65536 + (size_t)d * 256 + kk + s * 8);
      else          v = *(const bf16x8*)(Wbf + (size_t)d * 512 + kk + s * 8);
      *(bf16x8*)(sB + d * 144 + s * 16) = v;
    }
    __syncthreads();
    #pragma unroll
    for (int sub = 0; sub < 2; ++sub) {
      bf16x8 a[2], bb[8];
      #pragma unroll
      for (int m = 0; m < 2; ++m) {
        int row = wm * 32 + m * 16 + lr;
        a[m] = *(const bf16x8*)(sA + row * 144 + sub * 64 + lg * 16);
      }
      #pragma unroll
      for (int n = 0; n < 8; ++n) {
        int d = wn * 128 + n * 16 + lr;
        bb[n] = *(const bf16x8*)(sB + d * 144 + sub * 64 + lg * 16);
      }
      #pragma unroll
      for (int m = 0; m < 2; ++m) {
        #pragma unroll
        for (int n = 0; n < 8; ++n)
          acc[m][n] = __builtin_amdgcn_mfma_f32_16x16x32_bf16(a[m], bb[n], acc[m][n], 0, 0, 0);
      }
    }
  }

  #pragma unroll
  for (int m = 0; m < 2; ++m) {
    int rl = wm * 32 + m * 16 + lg * 4;
    #pragma unroll
    for (int n = 0; n < 8; ++n) {
      int d = wn * 128 + n * 16 + lr;
      float bs = sBias[d];
      #pragma unroll
      for (int r = 0; r < 4; ++r) {
        int row = rl + r;
        out[((size_t)b * 256 + i0 + row) * 256 + d] = acc[m][n][r] + bs;
      }
    }
  }
}

extern "C" void kernel_launch(void* const* d_in, const int* in_sizes, int n_in,
                              void* d_out, int out_size, void* d_ws, size_t ws_size,
                              hipStream_t stream) {
  const float* hidden  = (const float*)d_in[0];
  const float* dist    = (const float*)d_in[1];
  const float* bear    = (const float*)d_in[2];
  const float* head    = (const float*)d_in[3];
  const float* seqmask = (const float*)d_in[4];
  const float* domain  = (const float*)d_in[5];
  const float* W       = (const float*)d_in[6];
  const float* bias    = (const float*)d_in[7];
  float* out = (float*)d_out;

  char* ws = (char*)d_ws;
  short* Wbf   = (short*)ws;                                 // 512 KB
  float* flag  = (float*)(ws + 524288);                      // 2 floats
  short* P1T   = (short*)(ws + (1u << 20));                  // 32 MB
  short* weBuf = (short*)(ws + (1u << 20) + (32u << 20));    // 32 MB

  k0_pack<<<128, 256, 0, stream>>>(W, Wbf);
  k0_check<<<1, 256, 0, stream>>>(domain, flag);
  k1_proj<<<1024, 512, 46080, stream>>>(hidden, Wbf, P1T);
  k2a_weights<<<2048, 256, 0, stream>>>(dist, bear, head, seqmask, domain, flag, weBuf);
  k2b_gemm<<<512, 512, 56320, stream>>>(weBuf, hidden, P1T, Wbf, bias, out);
}